// Round 10
// baseline (560.682 us; speedup 1.0000x reference)
//
#include <hip/hip_runtime.h>
#include <math.h>

constexpr int NN   = 20000;
constexpr int FM   = 128;
constexpr int NH   = 8;
constexpr int HF   = NH * FM;     // 1024
constexpr int EE   = 160000;
constexpr int ET   = EE + NN;     // 180000 (edges + self loops)
constexpr int OC   = 128;
constexpr int CIRC = 504;
constexpr int MIRN = NN - CIRC;   // 19496
constexpr float NEG = 0.2f;

constexpr size_t OFF_CIRC = (size_t)CIRC * MIRN;            // 9,825,984
constexpr size_t OFF_MIR  = OFF_CIRC + (size_t)CIRC * OC;   // 9,890,496

typedef __attribute__((ext_vector_type(8))) short bf16x8;
typedef __attribute__((ext_vector_type(4))) float f32x4;

__device__ __forceinline__ int rl_i(int v, int lane) {
  return __builtin_amdgcn_readlane(v, lane);
}
__device__ __forceinline__ unsigned short bf16_rne(float x) {
  unsigned u = __float_as_uint(x);
  return (unsigned short)((u + 0x7FFFu + ((u >> 16) & 1u)) >> 16);
}
__device__ __forceinline__ float blo(unsigned u) { return __uint_as_float(u << 16); }
__device__ __forceinline__ float bhi(unsigned u) { return __uint_as_float(u & 0xFFFF0000u); }

// ---------------- CSR build ----------------
__global__ void k_init_counts(int* __restrict__ cnt) {
  int i = blockIdx.x * blockDim.x + threadIdx.x;
  if (i < NN) cnt[i] = 1;  // self loop
}

__global__ void k_count(const int* __restrict__ ei, int* __restrict__ cnt) {
  int e = blockIdx.x * blockDim.x + threadIdx.x;
  if (e < EE) atomicAdd(&cnt[ei[EE + e]], 1);
}

__global__ __launch_bounds__(1024) void k_scan(const int* __restrict__ cnt,
                                               int* __restrict__ rs,
                                               int* __restrict__ cur) {
  __shared__ int part[1024];
  const int t = threadIdx.x;
  const int SEG = (NN + 1023) / 1024;  // 20
  int lo = t * SEG, hi = min(NN, lo + SEG);
  int s = 0;
  for (int i = lo; i < hi; ++i) s += cnt[i];
  part[t] = s;
  __syncthreads();
  for (int off = 1; off < 1024; off <<= 1) {
    int v = 0;
    if (t >= off) v = part[t - off];
    __syncthreads();
    part[t] += v;
    __syncthreads();
  }
  int run = (t == 0) ? 0 : part[t - 1];
  for (int i = lo; i < hi; ++i) {
    int c = cnt[i];
    rs[i] = run;
    cur[i] = run;
    run += c;
  }
  if (t == 1023) rs[NN] = part[1023];
}

__global__ void k_fill(const int* __restrict__ ei, int* __restrict__ cur,
                       int* __restrict__ csrc) {
  int i = blockIdx.x * blockDim.x + threadIdx.x;
  if (i >= ET) return;
  int s, d;
  if (i < EE) { s = ei[i]; d = ei[EE + i]; }
  else        { s = i - EE; d = s; }
  int p = atomicAdd(&cur[d], 1);
  csrc[p] = s;
}

// ---- W prep: transpose [128][1024] -> [1024][128], split fp32 -> bf16 hi/lo
__global__ void k_prep_w(const float* __restrict__ W,
                         unsigned short* __restrict__ WThi,
                         unsigned short* __restrict__ WTlo) {
  int i = blockIdx.x * blockDim.x + threadIdx.x;
  if (i >= FM * HF) return;
  int k = i >> 10, n = i & 1023;
  float v = W[i];
  unsigned short h = bf16_rne(v);
  WThi[(size_t)n * FM + k] = h;
  WTlo[(size_t)n * FM + k] = bf16_rne(v - blo(h));
}

// ---- X split: fp32 [NN][128] -> bf16 hi/lo (same layout) ----
__global__ void k_split_x(const float* __restrict__ X,
                          unsigned short* __restrict__ Xhi,
                          unsigned short* __restrict__ Xlo) {
  int i = blockIdx.x * blockDim.x + threadIdx.x;
  if (i >= NN * FM) return;
  float v = X[i];
  unsigned short h = bf16_rne(v);
  Xhi[i] = h;
  Xlo[i] = bf16_rne(v - blo(h));
}

// ---- h = X @ W via 3-pass split-bf16 MFMA (~fp32 precision) ----
// block: 16 rows x 1024 cols; wave wq owns 256 cols (= heads 2wq, 2wq+1).
// Fused epilogue: bf16 H16 store + fp32 attn dots s,d.
__global__ __launch_bounds__(256) void k_gemm_mfma(
    const unsigned short* __restrict__ Xhi, const unsigned short* __restrict__ Xlo,
    const unsigned short* __restrict__ WThi, const unsigned short* __restrict__ WTlo,
    const float* __restrict__ Asc, const float* __restrict__ Adc,
    unsigned short* __restrict__ H16, float* __restrict__ Sv,
    float* __restrict__ Dv) {
  const int lane = threadIdx.x & 63;
  const int wq   = threadIdx.x >> 6;   // N-quarter 0..3
  const int m0   = blockIdx.x * 16;
  const int ri   = lane & 15;          // A-row / B-col selector
  const int kg   = lane >> 4;          // k-group (8 k each)

  // A fragments: lane holds X[m0+ri][kg*8 + ks*32 .. +8]
  bf16x8 Ah[4], Al[4];
  const unsigned short* xb = Xhi + (size_t)(m0 + ri) * FM + kg * 8;
  const unsigned short* xl = Xlo + (size_t)(m0 + ri) * FM + kg * 8;
#pragma unroll
  for (int ks = 0; ks < 4; ++ks) {
    Ah[ks] = *reinterpret_cast<const bf16x8*>(xb + ks * 32);
    Al[ks] = *reinterpret_cast<const bf16x8*>(xl + ks * 32);
  }
  float sacc[2][4] = {}, dacc[2][4] = {};
  for (int ct = 0; ct < 16; ++ct) {
    const int gc = wq * 256 + ct * 16 + ri;  // global col
    const unsigned short* wb = WThi + (size_t)gc * FM + kg * 8;
    const unsigned short* wl = WTlo + (size_t)gc * FM + kg * 8;
    f32x4 a0 = {0.f, 0.f, 0.f, 0.f}, a1 = a0, a2 = a0;  // 3 indep chains
#pragma unroll
    for (int ks = 0; ks < 4; ++ks) {
      bf16x8 Bh = *reinterpret_cast<const bf16x8*>(wb + ks * 32);
      bf16x8 Bl = *reinterpret_cast<const bf16x8*>(wl + ks * 32);
      a0 = __builtin_amdgcn_mfma_f32_16x16x32_bf16(Ah[ks], Bh, a0, 0, 0, 0);
      a1 = __builtin_amdgcn_mfma_f32_16x16x32_bf16(Al[ks], Bh, a1, 0, 0, 0);
      a2 = __builtin_amdgcn_mfma_f32_16x16x32_bf16(Ah[ks], Bl, a2, 0, 0, 0);
    }
    const int hh = ct >> 3;               // head-half within wave
    const float as_ = Asc[(wq * 2 + hh) * FM + (gc & 127)];
    const float ad_ = Adc[(wq * 2 + hh) * FM + (gc & 127)];
#pragma unroll
    for (int r = 0; r < 4; ++r) {
      float v = a0[r] + a1[r] + a2[r];
      int m = m0 + kg * 4 + r;            // C/D: row=(lane>>4)*4+reg, col=lane&15
      H16[(size_t)m * HF + gc] = bf16_rne(v);
      sacc[hh][r] += v * as_;
      dacc[hh][r] += v * ad_;
    }
  }
  // reduce s/d over 16 lanes (cols) per row-group, write per (row, head)
#pragma unroll
  for (int hh = 0; hh < 2; ++hh)
#pragma unroll
    for (int r = 0; r < 4; ++r) {
      float s = sacc[hh][r], d = dacc[hh][r];
#pragma unroll
      for (int mo = 1; mo <= 8; mo <<= 1) {
        s += __shfl_xor(s, mo, 64);
        d += __shfl_xor(d, mo, 64);
      }
      if (ri == 0) {
        int m = m0 + kg * 4 + r;
        Sv[m * NH + wq * 2 + hh] = s;
        Dv[m * NH + wq * 2 + hh] = d;
      }
    }
}

// ---------------- per-dst online-softmax aggregation (1 wave / node) -------
// softmax lanes: (edge j = lane>>3, head h = lane&7); gather: bf16 rows,
// lane covers heads (lane>>4, +4) x feats [(lane&15)*8, +8).
// Also emits bf16 hi/lo splits of the output (next layer's GEMM input).
__global__ __launch_bounds__(256) void k_agg(const unsigned short* __restrict__ H16,
                                             const float* __restrict__ Sv,
                                             const float* __restrict__ Dv,
                                             const int* __restrict__ rs,
                                             const int* __restrict__ csrc,
                                             const float* __restrict__ bias,
                                             float* __restrict__ Xo,
                                             unsigned short* __restrict__ XhiO,
                                             unsigned short* __restrict__ XloO) {
  const int wave = threadIdx.x >> 6;
  const int lane = threadIdx.x & 63;
  const int n = blockIdx.x * 4 + wave;
  if (n >= NN) return;
  const int r0 = rs[n];
  const int deg = rs[n + 1] - r0;   // >= 1 (self loop)
  const int j = lane >> 3, h = lane & 7;
  const int h0 = lane >> 4;         // 0..3
  const int boff = h0 * FM + (lane & 15) * 8;  // ushort offset of load0
  const float dvh = Dv[n * 8 + h];

  float m = -INFINITY, l = 0.f;
  float4 acc[4];  // [0..1]: head h0 feats 8; [2..3]: head h0+4 feats 8
#pragma unroll
  for (int q = 0; q < 4; ++q) acc[q] = make_float4(0.f, 0.f, 0.f, 0.f);

  for (int base = 0; base < deg; base += 8) {
    const int cnt = deg - base;
    int sj = csrc[r0 + min(base + j, deg - 1)];
    float lg = (j < cnt) ? (Sv[sj * 8 + h] + dvh) : -INFINITY;
    lg = lg > 0.f ? lg : NEG * lg;
    float cm = lg;
    cm = fmaxf(cm, __shfl_xor(cm, 8, 64));
    cm = fmaxf(cm, __shfl_xor(cm, 16, 64));
    cm = fmaxf(cm, __shfl_xor(cm, 32, 64));
    float mn = fmaxf(m, cm);
    float fs = expf(m - mn);     // first chunk: exp(-inf)=0
    float p = expf(lg - mn);     // inactive: exp(-inf)=0
    float cs = p;
    cs += __shfl_xor(cs, 8, 64);
    cs += __shfl_xor(cs, 16, 64);
    cs += __shfl_xor(cs, 32, 64);
    l = l * fs + cs;
    m = mn;
    float f0 = __shfl(fs, h0, 64);      // fs of head h0 (lives in lane h0)
    float f1 = __shfl(fs, h0 + 4, 64);  // fs of head h0+4
    acc[0].x *= f0; acc[0].y *= f0; acc[0].z *= f0; acc[0].w *= f0;
    acc[1].x *= f0; acc[1].y *= f0; acc[1].z *= f0; acc[1].w *= f0;
    acc[2].x *= f1; acc[2].y *= f1; acc[2].z *= f1; acc[2].w *= f1;
    acc[3].x *= f1; acc[3].y *= f1; acc[3].z *= f1; acc[3].w *= f1;
#pragma unroll
    for (int jj = 0; jj < 8; ++jj) {
      if (jj < cnt) {
        int se = rl_i(sj, jj * 8);
        const uint4* hp = reinterpret_cast<const uint4*>(H16 + (size_t)se * HF + boff);
        uint4 v0 = hp[0];
        uint4 v1 = hp[64];  // +64 uint4 = +512 ushorts = head h0+4
        float pe0 = __shfl(p, jj * 8 + h0, 64);
        float pe1 = __shfl(p, jj * 8 + h0 + 4, 64);
        acc[0].x += pe0 * blo(v0.x); acc[0].y += pe0 * bhi(v0.x);
        acc[0].z += pe0 * blo(v0.y); acc[0].w += pe0 * bhi(v0.y);
        acc[1].x += pe0 * blo(v0.z); acc[1].y += pe0 * bhi(v0.z);
        acc[1].z += pe0 * blo(v0.w); acc[1].w += pe0 * bhi(v0.w);
        acc[2].x += pe1 * blo(v1.x); acc[2].y += pe1 * bhi(v1.x);
        acc[2].z += pe1 * blo(v1.y); acc[2].w += pe1 * bhi(v1.y);
        acc[3].x += pe1 * blo(v1.z); acc[3].y += pe1 * bhi(v1.z);
        acc[3].z += pe1 * blo(v1.w); acc[3].w += pe1 * bhi(v1.w);
      }
    }
  }
  // divide by per-head denom, sum over heads (xor 16/32 folds head groups)
  float inv0 = 1.0f / (__shfl(l, h0, 64) + 1e-16f);
  float inv1 = 1.0f / (__shfl(l, h0 + 4, 64) + 1e-16f);
  float o[8];
  o[0] = acc[0].x * inv0 + acc[2].x * inv1;
  o[1] = acc[0].y * inv0 + acc[2].y * inv1;
  o[2] = acc[0].z * inv0 + acc[2].z * inv1;
  o[3] = acc[0].w * inv0 + acc[2].w * inv1;
  o[4] = acc[1].x * inv0 + acc[3].x * inv1;
  o[5] = acc[1].y * inv0 + acc[3].y * inv1;
  o[6] = acc[1].z * inv0 + acc[3].z * inv1;
  o[7] = acc[1].w * inv0 + acc[3].w * inv1;
#pragma unroll
  for (int k = 0; k < 8; ++k) {
    o[k] += __shfl_xor(o[k], 16, 64);
    o[k] += __shfl_xor(o[k], 32, 64);
  }
  if (lane < 16) {
    const int f0i = lane * 8;
    float vals[8];
    union { unsigned short us[8]; uint4 v; } ph, pl;
#pragma unroll
    for (int k = 0; k < 8; ++k) {
      float bv = bias[f0i + k];
      vals[k] = fmaxf(o[k] * 0.125f + bv, 0.f);
      unsigned short hh = bf16_rne(vals[k]);
      ph.us[k] = hh;
      pl.us[k] = bf16_rne(vals[k] - blo(hh));
    }
    float4 w0 = make_float4(vals[0], vals[1], vals[2], vals[3]);
    float4 w1 = make_float4(vals[4], vals[5], vals[6], vals[7]);
    *reinterpret_cast<float4*>(Xo + (size_t)n * FM + f0i) = w0;
    *reinterpret_cast<float4*>(Xo + (size_t)n * FM + f0i + 4) = w1;
    *reinterpret_cast<uint4*>(XhiO + (size_t)n * FM + f0i) = ph.v;
    *reinterpret_cast<uint4*>(XloO + (size_t)n * FM + f0i) = pl.v;
  }
}

// ---------------- Wc transpose: WcT[c*128+k][o] = Wc[o][c][k] ----------------
__global__ void k_transpose_wc(const float* __restrict__ Wc, float* __restrict__ WcT) {
  int i = blockIdx.x * blockDim.x + threadIdx.x;
  if (i < OC * 2 * FM) {
    int o = i / (2 * FM), k = i % (2 * FM);
    WcT[k * OC + o] = Wc[i];
  }
}

// ---------------- emb = [x1|x2] @ WcT + bc; write circ/mir slices of out ----
__global__ __launch_bounds__(256) void k_emb(const float* __restrict__ X1,
                                             const float* __restrict__ X2,
                                             const float* __restrict__ WcT,
                                             const float* __restrict__ bc,
                                             float* __restrict__ Out) {
  __shared__ float xs[64][129];
  const int t = threadIdx.x;
  const int row0 = blockIdx.x * 64;
  const int tr = (t >> 5) << 3;  // 8 rows
  const int tc = (t & 31) << 2;  // 4 cols
  float acc[8][4] = {};
  for (int half = 0; half < 2; ++half) {
    const float* Xs = half ? X2 : X1;
    __syncthreads();  // protect xs reuse across halves
#pragma unroll
    for (int it = 0; it < 8; ++it) {
      int f4 = it * 256 + t;  // 2048 float4 = 64 x 128
      int r = f4 >> 5;
      int c = (f4 & 31) << 2;
      int gr = row0 + r;
      float4 v = make_float4(0.f, 0.f, 0.f, 0.f);
      if (gr < NN) v = *reinterpret_cast<const float4*>(Xs + (size_t)gr * FM + c);
      xs[r][c] = v.x; xs[r][c + 1] = v.y; xs[r][c + 2] = v.z; xs[r][c + 3] = v.w;
    }
    __syncthreads();
    const float* Wp = WcT + (size_t)half * FM * OC;
    for (int kk = 0; kk < FM; ++kk) {
      float4 b = *reinterpret_cast<const float4*>(Wp + kk * OC + tc);
      float av[8];
#pragma unroll
      for (int r = 0; r < 8; ++r) av[r] = xs[tr + r][kk];
#pragma unroll
      for (int r = 0; r < 8; ++r) {
        acc[r][0] += av[r] * b.x;
        acc[r][1] += av[r] * b.y;
        acc[r][2] += av[r] * b.z;
        acc[r][3] += av[r] * b.w;
      }
    }
  }
  float4 bcv = *reinterpret_cast<const float4*>(bc + tc);
#pragma unroll
  for (int r = 0; r < 8; ++r) {
    int gr = row0 + tr + r;
    if (gr < NN) {
      float4 o;
      o.x = acc[r][0] + bcv.x;
      o.y = acc[r][1] + bcv.y;
      o.z = acc[r][2] + bcv.z;
      o.w = acc[r][3] + bcv.w;
      float* dst = (gr < CIRC)
                       ? (Out + OFF_CIRC + (size_t)gr * OC + tc)
                       : (Out + OFF_MIR + (size_t)(gr - CIRC) * OC + tc);
      *reinterpret_cast<float4*>(dst) = o;
    }
  }
}

// ---------------- out1 = circ @ mir.T (504 x 19496, K=128) ----------------
__global__ __launch_bounds__(256) void k_outer(const float* __restrict__ A,
                                               const float* __restrict__ B,
                                               float* __restrict__ C) {
  __shared__ float As[64][65];
  __shared__ float Bs[64][65];
  const int t = threadIdx.x;
  const int i0 = blockIdx.y * 64;
  const int j0 = blockIdx.x * 64;
  const int tx = t & 15, ty = t >> 4;
  float acc[4][4] = {};
  for (int kh = 0; kh < 2; ++kh) {
    __syncthreads();
#pragma unroll
    for (int it = 0; it < 4; ++it) {
      int f4 = it * 256 + t;   // 1024 float4 = 64 rows x 16
      int r = f4 >> 4;
      int c = (f4 & 15) << 2;
      float4 v = make_float4(0.f, 0.f, 0.f, 0.f);
      if (i0 + r < CIRC)
        v = *reinterpret_cast<const float4*>(A + (size_t)(i0 + r) * OC + kh * 64 + c);
      As[r][c] = v.x; As[r][c + 1] = v.y; As[r][c + 2] = v.z; As[r][c + 3] = v.w;
      float4 w = make_float4(0.f, 0.f, 0.f, 0.f);
      if (j0 + r < MIRN)
        w = *reinterpret_cast<const float4*>(B + (size_t)(j0 + r) * OC + kh * 64 + c);
      Bs[r][c] = w.x; Bs[r][c + 1] = w.y; Bs[r][c + 2] = w.z; Bs[r][c + 3] = w.w;
    }
    __syncthreads();
    for (int kk = 0; kk < 64; ++kk) {
      float a[4], b[4];
#pragma unroll
      for (int r = 0; r < 4; ++r) a[r] = As[ty * 4 + r][kk];
#pragma unroll
      for (int c = 0; c < 4; ++c) b[c] = Bs[tx * 4 + c][kk];
#pragma unroll
      for (int r = 0; r < 4; ++r)
#pragma unroll
        for (int c = 0; c < 4; ++c) acc[r][c] += a[r] * b[c];
    }
  }
#pragma unroll
  for (int r = 0; r < 4; ++r) {
    int i = i0 + ty * 4 + r;
    if (i >= CIRC) break;
#pragma unroll
    for (int c = 0; c < 4; ++c) {
      int j = j0 + tx * 4 + c;
      if (j < MIRN) C[(size_t)i * MIRN + j] = acc[r][c];
    }
  }
}

// ---------------- launcher ----------------
static inline size_t alignup(size_t v) { return (v + 255) & ~(size_t)255; }

extern "C" void kernel_launch(void* const* d_in, const int* in_sizes, int n_in,
                              void* d_out, int out_size, void* d_ws, size_t ws_size,
                              hipStream_t stream) {
  const float* x   = (const float*)d_in[0];
  const int*   ei  = (const int*)d_in[1];
  const float* W1  = (const float*)d_in[2];
  const float* as1 = (const float*)d_in[3];
  const float* ad1 = (const float*)d_in[4];
  const float* b1  = (const float*)d_in[5];
  const float* W2  = (const float*)d_in[6];
  const float* as2 = (const float*)d_in[7];
  const float* ad2 = (const float*)d_in[8];
  const float* b2  = (const float*)d_in[9];
  const float* Wc  = (const float*)d_in[10];
  const float* bc  = (const float*)d_in[11];
  float* out = (float*)d_out;

  char* w = (char*)d_ws;
  size_t off = 0;
  unsigned short* H16  = (unsigned short*)(w + off); off = alignup(off + (size_t)NN * HF * 2);
  unsigned short* Xhi  = (unsigned short*)(w + off); off = alignup(off + (size_t)NN * FM * 2);
  unsigned short* Xlo  = (unsigned short*)(w + off); off = alignup(off + (size_t)NN * FM * 2);
  unsigned short* WThi = (unsigned short*)(w + off); off = alignup(off + (size_t)HF * FM * 2);
  unsigned short* WTlo = (unsigned short*)(w + off); off = alignup(off + (size_t)HF * FM * 2);
  float* Sbuf = (float*)(w + off); off = alignup(off + (size_t)NN * NH * 4);
  float* Dbuf = (float*)(w + off); off = alignup(off + (size_t)NN * NH * 4);
  float* X1   = (float*)(w + off); off = alignup(off + (size_t)NN * FM * 4);
  float* X2   = (float*)(w + off); off = alignup(off + (size_t)NN * FM * 4);
  float* WcT  = (float*)(w + off); off = alignup(off + (size_t)OC * 2 * FM * 4);
  int* counts = (int*)(w + off);   off = alignup(off + (size_t)NN * 4);
  int* rowst  = (int*)(w + off);   off = alignup(off + (size_t)(NN + 1) * 4);
  int* cursor = (int*)(w + off);   off = alignup(off + (size_t)NN * 4);
  int* csrsrc = (int*)(w + off);   off = alignup(off + (size_t)ET * 4);

  // CSR by dst (rebuilt every call; ws is re-poisoned)
  k_init_counts<<<(NN + 255) / 256, 256, 0, stream>>>(counts);
  k_count<<<(EE + 255) / 256, 256, 0, stream>>>(ei, counts);
  k_scan<<<1, 1024, 0, stream>>>(counts, rowst, cursor);
  k_fill<<<(ET + 255) / 256, 256, 0, stream>>>(ei, cursor, csrsrc);

  // layer 1
  k_prep_w<<<(FM * HF + 255) / 256, 256, 0, stream>>>(W1, WThi, WTlo);
  k_split_x<<<(NN * FM + 255) / 256, 256, 0, stream>>>(x, Xhi, Xlo);
  k_gemm_mfma<<<NN / 16, 256, 0, stream>>>(Xhi, Xlo, WThi, WTlo, as1, ad1,
                                           H16, Sbuf, Dbuf);
  k_agg<<<(NN + 3) / 4, 256, 0, stream>>>(H16, Sbuf, Dbuf, rowst, csrsrc, b1,
                                          X1, Xhi, Xlo);
  // layer 2
  k_prep_w<<<(FM * HF + 255) / 256, 256, 0, stream>>>(W2, WThi, WTlo);
  k_gemm_mfma<<<NN / 16, 256, 0, stream>>>(Xhi, Xlo, WThi, WTlo, as2, ad2,
                                           H16, Sbuf, Dbuf);
  k_agg<<<(NN + 3) / 4, 256, 0, stream>>>(H16, Sbuf, Dbuf, rowst, csrsrc, b2,
                                          X2, Xhi, Xlo);
  // classifier + outputs
  k_transpose_wc<<<(OC * 2 * FM + 255) / 256, 256, 0, stream>>>(Wc, WcT);
  k_emb<<<(NN + 63) / 64, 256, 0, stream>>>(X1, X2, WcT, bc, out);
  k_outer<<<dim3((MIRN + 63) / 64, (CIRC + 63) / 64), 256, 0, stream>>>(
      out + OFF_CIRC, out + OFF_MIR, out);
}

// Round 11
// 516.149 us; speedup vs baseline: 1.0863x; 1.0863x over previous
//
#include <hip/hip_runtime.h>
#include <math.h>

constexpr int NN   = 20000;
constexpr int FM   = 128;
constexpr int NH   = 8;
constexpr int HF   = NH * FM;     // 1024
constexpr int EE   = 160000;
constexpr int ET   = EE + NN;     // 180000 (edges + self loops)
constexpr int OC   = 128;
constexpr int CIRC = 504;
constexpr int MIRN = NN - CIRC;   // 19496
constexpr float NEG = 0.2f;

constexpr size_t OFF_CIRC = (size_t)CIRC * MIRN;            // 9,825,984
constexpr size_t OFF_MIR  = OFF_CIRC + (size_t)CIRC * OC;   // 9,890,496

typedef __attribute__((ext_vector_type(8))) short bf16x8;
typedef __attribute__((ext_vector_type(4))) float f32x4;

__device__ __forceinline__ int rl_i(int v, int lane) {
  return __builtin_amdgcn_readlane(v, lane);
}
__device__ __forceinline__ unsigned short bf16_rne(float x) {
  unsigned u = __float_as_uint(x);
  return (unsigned short)((u + 0x7FFFu + ((u >> 16) & 1u)) >> 16);
}
__device__ __forceinline__ float blo(unsigned u) { return __uint_as_float(u << 16); }
__device__ __forceinline__ float bhi(unsigned u) { return __uint_as_float(u & 0xFFFF0000u); }

// ---------------- CSR build ----------------
__global__ void k_init_counts(int* __restrict__ cnt) {
  int i = blockIdx.x * blockDim.x + threadIdx.x;
  if (i < NN) cnt[i] = 1;  // self loop
}

__global__ void k_count(const int* __restrict__ ei, int* __restrict__ cnt) {
  int e = blockIdx.x * blockDim.x + threadIdx.x;
  if (e < EE) atomicAdd(&cnt[ei[EE + e]], 1);
}

__global__ __launch_bounds__(1024) void k_scan(const int* __restrict__ cnt,
                                               int* __restrict__ rs,
                                               int* __restrict__ cur) {
  __shared__ int part[1024];
  const int t = threadIdx.x;
  const int SEG = (NN + 1023) / 1024;  // 20
  int lo = t * SEG, hi = min(NN, lo + SEG);
  int s = 0;
  for (int i = lo; i < hi; ++i) s += cnt[i];
  part[t] = s;
  __syncthreads();
  for (int off = 1; off < 1024; off <<= 1) {
    int v = 0;
    if (t >= off) v = part[t - off];
    __syncthreads();
    part[t] += v;
    __syncthreads();
  }
  int run = (t == 0) ? 0 : part[t - 1];
  for (int i = lo; i < hi; ++i) {
    int c = cnt[i];
    rs[i] = run;
    cur[i] = run;
    run += c;
  }
  if (t == 1023) rs[NN] = part[1023];
}

__global__ void k_fill(const int* __restrict__ ei, int* __restrict__ cur,
                       int* __restrict__ csrc) {
  int i = blockIdx.x * blockDim.x + threadIdx.x;
  if (i >= ET) return;
  int s, d;
  if (i < EE) { s = ei[i]; d = ei[EE + i]; }
  else        { s = i - EE; d = s; }
  int p = atomicAdd(&cur[d], 1);
  csrc[p] = s;
}

// ---- W prep: transpose [128][1024] -> [1024][128], split fp32 -> bf16 hi/lo
__global__ void k_prep_w(const float* __restrict__ W,
                         unsigned short* __restrict__ WThi,
                         unsigned short* __restrict__ WTlo) {
  int i = blockIdx.x * blockDim.x + threadIdx.x;
  if (i >= FM * HF) return;
  int k = i >> 10, n = i & 1023;
  float v = W[i];
  unsigned short h = bf16_rne(v);
  WThi[(size_t)n * FM + k] = h;
  WTlo[(size_t)n * FM + k] = bf16_rne(v - blo(h));
}

// ---- X split: fp32 [NN][128] -> bf16 hi/lo (same layout) ----
__global__ void k_split_x(const float* __restrict__ X,
                          unsigned short* __restrict__ Xhi,
                          unsigned short* __restrict__ Xlo) {
  int i = blockIdx.x * blockDim.x + threadIdx.x;
  if (i >= NN * FM) return;
  float v = X[i];
  unsigned short h = bf16_rne(v);
  Xhi[i] = h;
  Xlo[i] = bf16_rne(v - blo(h));
}

// ---- zero the attention dot buffers (accumulated via atomics) ----
__global__ void k_zero_sd(float* __restrict__ Sv, float* __restrict__ Dv) {
  int i = blockIdx.x * blockDim.x + threadIdx.x;
  if (i < NN * NH) { Sv[i] = 0.f; Dv[i] = 0.f; }
}

// ---- h = X @ W via split-bf16 MFMA (~fp32 precision) ----
// block: 64 rows x 256 cols, 4 waves; wave owns 64x64 (4x4 tiles of 16x16).
// All 3 split products accumulate into one fp32 acc chain; 16 indep chains.
// Epilogue: bf16 H16 store + partial attn dots s,d via atomicAdd.
__global__ __launch_bounds__(256) void k_gemm_mfma(
    const unsigned short* __restrict__ Xhi, const unsigned short* __restrict__ Xlo,
    const unsigned short* __restrict__ WThi, const unsigned short* __restrict__ WTlo,
    const float* __restrict__ Asc, const float* __restrict__ Adc,
    unsigned short* __restrict__ H16, float* __restrict__ Sv,
    float* __restrict__ Dv) {
  const int lane = threadIdx.x & 63;
  const int w    = threadIdx.x >> 6;        // wave 0..3
  const int m0   = blockIdx.x * 64;
  const int c0   = blockIdx.y * 256 + w * 64;
  const int ri   = lane & 15;               // A-row / B-col selector
  const int kg   = lane >> 4;               // k-group (8 k each)

  f32x4 acc[4][4];
#pragma unroll
  for (int mt = 0; mt < 4; ++mt)
#pragma unroll
    for (int nt = 0; nt < 4; ++nt) acc[mt][nt] = {0.f, 0.f, 0.f, 0.f};

  for (int ks = 0; ks < 4; ++ks) {
    const int ko = ks * 32 + kg * 8;
    bf16x8 Ah[4], Al[4], Bh[4], Bl[4];
#pragma unroll
    for (int mt = 0; mt < 4; ++mt) {
      int row = min(m0 + mt * 16 + ri, NN - 1);
      Ah[mt] = *reinterpret_cast<const bf16x8*>(Xhi + (size_t)row * FM + ko);
      Al[mt] = *reinterpret_cast<const bf16x8*>(Xlo + (size_t)row * FM + ko);
    }
#pragma unroll
    for (int nt = 0; nt < 4; ++nt) {
      int col = c0 + nt * 16 + ri;
      Bh[nt] = *reinterpret_cast<const bf16x8*>(WThi + (size_t)col * FM + ko);
      Bl[nt] = *reinterpret_cast<const bf16x8*>(WTlo + (size_t)col * FM + ko);
    }
#pragma unroll
    for (int mt = 0; mt < 4; ++mt)
#pragma unroll
      for (int nt = 0; nt < 4; ++nt) {
        acc[mt][nt] = __builtin_amdgcn_mfma_f32_16x16x32_bf16(Ah[mt], Bh[nt], acc[mt][nt], 0, 0, 0);
        acc[mt][nt] = __builtin_amdgcn_mfma_f32_16x16x32_bf16(Al[mt], Bh[nt], acc[mt][nt], 0, 0, 0);
        acc[mt][nt] = __builtin_amdgcn_mfma_f32_16x16x32_bf16(Ah[mt], Bl[nt], acc[mt][nt], 0, 0, 0);
      }
  }

  // ---- epilogue: H16 store + s/d partial dots ----
  const int hd   = c0 >> 7;        // head (wave's 64 cols lie in one head)
  const int cih0 = c0 & 127;       // col-in-head base
  float asv[4], adv[4];
#pragma unroll
  for (int nt = 0; nt < 4; ++nt) {
    int cih = cih0 + nt * 16 + ri;
    asv[nt] = Asc[hd * FM + cih];
    adv[nt] = Adc[hd * FM + cih];
  }
#pragma unroll
  for (int mt = 0; mt < 4; ++mt) {
    float ssum[4] = {0.f, 0.f, 0.f, 0.f};
    float dsum[4] = {0.f, 0.f, 0.f, 0.f};
#pragma unroll
    for (int nt = 0; nt < 4; ++nt) {
      const int gc = c0 + nt * 16 + ri;
#pragma unroll
      for (int r = 0; r < 4; ++r) {
        float v = acc[mt][nt][r];
        int gr = m0 + mt * 16 + kg * 4 + r;  // C/D: row=(lane>>4)*4+reg, col=lane&15
        if (gr < NN) H16[(size_t)gr * HF + gc] = bf16_rne(v);
        ssum[r] += v * asv[nt];
        dsum[r] += v * adv[nt];
      }
    }
#pragma unroll
    for (int r = 0; r < 4; ++r) {
      float s = ssum[r], d = dsum[r];
#pragma unroll
      for (int mo = 1; mo <= 8; mo <<= 1) {
        s += __shfl_xor(s, mo, 64);
        d += __shfl_xor(d, mo, 64);
      }
      int gr = m0 + mt * 16 + kg * 4 + r;
      if (ri == 0 && gr < NN) {
        atomicAdd(&Sv[gr * NH + hd], s);
        atomicAdd(&Dv[gr * NH + hd], d);
      }
    }
  }
}

// ---------------- per-dst online-softmax aggregation (1 wave / node) -------
// softmax lanes: (edge j = lane>>3, head h = lane&7); gather: bf16 rows,
// lane covers heads (lane>>4, +4) x feats [(lane&15)*8, +8).
// Also emits bf16 hi/lo splits of the output (next layer's GEMM input).
__global__ __launch_bounds__(256) void k_agg(const unsigned short* __restrict__ H16,
                                             const float* __restrict__ Sv,
                                             const float* __restrict__ Dv,
                                             const int* __restrict__ rs,
                                             const int* __restrict__ csrc,
                                             const float* __restrict__ bias,
                                             float* __restrict__ Xo,
                                             unsigned short* __restrict__ XhiO,
                                             unsigned short* __restrict__ XloO) {
  const int wave = threadIdx.x >> 6;
  const int lane = threadIdx.x & 63;
  const int n = blockIdx.x * 4 + wave;
  if (n >= NN) return;
  const int r0 = rs[n];
  const int deg = rs[n + 1] - r0;   // >= 1 (self loop)
  const int j = lane >> 3, h = lane & 7;
  const int h0 = lane >> 4;         // 0..3
  const int boff = h0 * FM + (lane & 15) * 8;  // ushort offset of load0
  const float dvh = Dv[n * 8 + h];

  float m = -INFINITY, l = 0.f;
  float4 acc[4];  // [0..1]: head h0 feats 8; [2..3]: head h0+4 feats 8
#pragma unroll
  for (int q = 0; q < 4; ++q) acc[q] = make_float4(0.f, 0.f, 0.f, 0.f);

  for (int base = 0; base < deg; base += 8) {
    const int cnt = deg - base;
    int sj = csrc[r0 + min(base + j, deg - 1)];
    float lg = (j < cnt) ? (Sv[sj * 8 + h] + dvh) : -INFINITY;
    lg = lg > 0.f ? lg : NEG * lg;
    float cm = lg;
    cm = fmaxf(cm, __shfl_xor(cm, 8, 64));
    cm = fmaxf(cm, __shfl_xor(cm, 16, 64));
    cm = fmaxf(cm, __shfl_xor(cm, 32, 64));
    float mn = fmaxf(m, cm);
    float fs = expf(m - mn);     // first chunk: exp(-inf)=0
    float p = expf(lg - mn);     // inactive: exp(-inf)=0
    float cs = p;
    cs += __shfl_xor(cs, 8, 64);
    cs += __shfl_xor(cs, 16, 64);
    cs += __shfl_xor(cs, 32, 64);
    l = l * fs + cs;
    m = mn;
    float f0 = __shfl(fs, h0, 64);      // fs of head h0 (lives in lane h0)
    float f1 = __shfl(fs, h0 + 4, 64);  // fs of head h0+4
    acc[0].x *= f0; acc[0].y *= f0; acc[0].z *= f0; acc[0].w *= f0;
    acc[1].x *= f0; acc[1].y *= f0; acc[1].z *= f0; acc[1].w *= f0;
    acc[2].x *= f1; acc[2].y *= f1; acc[2].z *= f1; acc[2].w *= f1;
    acc[3].x *= f1; acc[3].y *= f1; acc[3].z *= f1; acc[3].w *= f1;
#pragma unroll
    for (int jj = 0; jj < 8; ++jj) {
      if (jj < cnt) {
        int se = rl_i(sj, jj * 8);
        const uint4* hp = reinterpret_cast<const uint4*>(H16 + (size_t)se * HF + boff);
        uint4 v0 = hp[0];
        uint4 v1 = hp[64];  // +64 uint4 = +512 ushorts = head h0+4
        float pe0 = __shfl(p, jj * 8 + h0, 64);
        float pe1 = __shfl(p, jj * 8 + h0 + 4, 64);
        acc[0].x += pe0 * blo(v0.x); acc[0].y += pe0 * bhi(v0.x);
        acc[0].z += pe0 * blo(v0.y); acc[0].w += pe0 * bhi(v0.y);
        acc[1].x += pe0 * blo(v0.z); acc[1].y += pe0 * bhi(v0.z);
        acc[1].z += pe0 * blo(v0.w); acc[1].w += pe0 * bhi(v0.w);
        acc[2].x += pe1 * blo(v1.x); acc[2].y += pe1 * bhi(v1.x);
        acc[2].z += pe1 * blo(v1.y); acc[2].w += pe1 * bhi(v1.y);
        acc[3].x += pe1 * blo(v1.z); acc[3].y += pe1 * bhi(v1.z);
        acc[3].z += pe1 * blo(v1.w); acc[3].w += pe1 * bhi(v1.w);
      }
    }
  }
  // divide by per-head denom, sum over heads (xor 16/32 folds head groups)
  float inv0 = 1.0f / (__shfl(l, h0, 64) + 1e-16f);
  float inv1 = 1.0f / (__shfl(l, h0 + 4, 64) + 1e-16f);
  float o[8];
  o[0] = acc[0].x * inv0 + acc[2].x * inv1;
  o[1] = acc[0].y * inv0 + acc[2].y * inv1;
  o[2] = acc[0].z * inv0 + acc[2].z * inv1;
  o[3] = acc[0].w * inv0 + acc[2].w * inv1;
  o[4] = acc[1].x * inv0 + acc[3].x * inv1;
  o[5] = acc[1].y * inv0 + acc[3].y * inv1;
  o[6] = acc[1].z * inv0 + acc[3].z * inv1;
  o[7] = acc[1].w * inv0 + acc[3].w * inv1;
#pragma unroll
  for (int k = 0; k < 8; ++k) {
    o[k] += __shfl_xor(o[k], 16, 64);
    o[k] += __shfl_xor(o[k], 32, 64);
  }
  if (lane < 16) {
    const int f0i = lane * 8;
    float vals[8];
    union { unsigned short us[8]; uint4 v; } ph, pl;
#pragma unroll
    for (int k = 0; k < 8; ++k) {
      float bv = bias[f0i + k];
      vals[k] = fmaxf(o[k] * 0.125f + bv, 0.f);
      unsigned short hh = bf16_rne(vals[k]);
      ph.us[k] = hh;
      pl.us[k] = bf16_rne(vals[k] - blo(hh));
    }
    float4 w0 = make_float4(vals[0], vals[1], vals[2], vals[3]);
    float4 w1 = make_float4(vals[4], vals[5], vals[6], vals[7]);
    *reinterpret_cast<float4*>(Xo + (size_t)n * FM + f0i) = w0;
    *reinterpret_cast<float4*>(Xo + (size_t)n * FM + f0i + 4) = w1;
    *reinterpret_cast<uint4*>(XhiO + (size_t)n * FM + f0i) = ph.v;
    *reinterpret_cast<uint4*>(XloO + (size_t)n * FM + f0i) = pl.v;
  }
}

// ---------------- Wc transpose: WcT[c*128+k][o] = Wc[o][c][k] ----------------
__global__ void k_transpose_wc(const float* __restrict__ Wc, float* __restrict__ WcT) {
  int i = blockIdx.x * blockDim.x + threadIdx.x;
  if (i < OC * 2 * FM) {
    int o = i / (2 * FM), k = i % (2 * FM);
    WcT[k * OC + o] = Wc[i];
  }
}

// ---------------- emb = [x1|x2] @ WcT + bc; write circ/mir slices of out ----
__global__ __launch_bounds__(256) void k_emb(const float* __restrict__ X1,
                                             const float* __restrict__ X2,
                                             const float* __restrict__ WcT,
                                             const float* __restrict__ bc,
                                             float* __restrict__ Out) {
  __shared__ float xs[64][129];
  const int t = threadIdx.x;
  const int row0 = blockIdx.x * 64;
  const int tr = (t >> 5) << 3;  // 8 rows
  const int tc = (t & 31) << 2;  // 4 cols
  float acc[8][4] = {};
  for (int half = 0; half < 2; ++half) {
    const float* Xs = half ? X2 : X1;
    __syncthreads();  // protect xs reuse across halves
#pragma unroll
    for (int it = 0; it < 8; ++it) {
      int f4 = it * 256 + t;  // 2048 float4 = 64 x 128
      int r = f4 >> 5;
      int c = (f4 & 31) << 2;
      int gr = row0 + r;
      float4 v = make_float4(0.f, 0.f, 0.f, 0.f);
      if (gr < NN) v = *reinterpret_cast<const float4*>(Xs + (size_t)gr * FM + c);
      xs[r][c] = v.x; xs[r][c + 1] = v.y; xs[r][c + 2] = v.z; xs[r][c + 3] = v.w;
    }
    __syncthreads();
    const float* Wp = WcT + (size_t)half * FM * OC;
    for (int kk = 0; kk < FM; ++kk) {
      float4 b = *reinterpret_cast<const float4*>(Wp + kk * OC + tc);
      float av[8];
#pragma unroll
      for (int r = 0; r < 8; ++r) av[r] = xs[tr + r][kk];
#pragma unroll
      for (int r = 0; r < 8; ++r) {
        acc[r][0] += av[r] * b.x;
        acc[r][1] += av[r] * b.y;
        acc[r][2] += av[r] * b.z;
        acc[r][3] += av[r] * b.w;
      }
    }
  }
  float4 bcv = *reinterpret_cast<const float4*>(bc + tc);
#pragma unroll
  for (int r = 0; r < 8; ++r) {
    int gr = row0 + tr + r;
    if (gr < NN) {
      float4 o;
      o.x = acc[r][0] + bcv.x;
      o.y = acc[r][1] + bcv.y;
      o.z = acc[r][2] + bcv.z;
      o.w = acc[r][3] + bcv.w;
      float* dst = (gr < CIRC)
                       ? (Out + OFF_CIRC + (size_t)gr * OC + tc)
                       : (Out + OFF_MIR + (size_t)(gr - CIRC) * OC + tc);
      *reinterpret_cast<float4*>(dst) = o;
    }
  }
}

// ---------------- out1 = circ @ mir.T (504 x 19496, K=128) ----------------
__global__ __launch_bounds__(256) void k_outer(const float* __restrict__ A,
                                               const float* __restrict__ B,
                                               float* __restrict__ C) {
  __shared__ float As[64][65];
  __shared__ float Bs[64][65];
  const int t = threadIdx.x;
  const int i0 = blockIdx.y * 64;
  const int j0 = blockIdx.x * 64;
  const int tx = t & 15, ty = t >> 4;
  float acc[4][4] = {};
  for (int kh = 0; kh < 2; ++kh) {
    __syncthreads();
#pragma unroll
    for (int it = 0; it < 4; ++it) {
      int f4 = it * 256 + t;   // 1024 float4 = 64 rows x 16
      int r = f4 >> 4;
      int c = (f4 & 15) << 2;
      float4 v = make_float4(0.f, 0.f, 0.f, 0.f);
      if (i0 + r < CIRC)
        v = *reinterpret_cast<const float4*>(A + (size_t)(i0 + r) * OC + kh * 64 + c);
      As[r][c] = v.x; As[r][c + 1] = v.y; As[r][c + 2] = v.z; As[r][c + 3] = v.w;
      float4 w = make_float4(0.f, 0.f, 0.f, 0.f);
      if (j0 + r < MIRN)
        w = *reinterpret_cast<const float4*>(B + (size_t)(j0 + r) * OC + kh * 64 + c);
      Bs[r][c] = w.x; Bs[r][c + 1] = w.y; Bs[r][c + 2] = w.z; Bs[r][c + 3] = w.w;
    }
    __syncthreads();
    for (int kk = 0; kk < 64; ++kk) {
      float a[4], b[4];
#pragma unroll
      for (int r = 0; r < 4; ++r) a[r] = As[ty * 4 + r][kk];
#pragma unroll
      for (int c = 0; c < 4; ++c) b[c] = Bs[tx * 4 + c][kk];
#pragma unroll
      for (int r = 0; r < 4; ++r)
#pragma unroll
        for (int c = 0; c < 4; ++c) acc[r][c] += a[r] * b[c];
    }
  }
#pragma unroll
  for (int r = 0; r < 4; ++r) {
    int i = i0 + ty * 4 + r;
    if (i >= CIRC) break;
#pragma unroll
    for (int c = 0; c < 4; ++c) {
      int j = j0 + tx * 4 + c;
      if (j < MIRN) C[(size_t)i * MIRN + j] = acc[r][c];
    }
  }
}

// ---------------- launcher ----------------
static inline size_t alignup(size_t v) { return (v + 255) & ~(size_t)255; }

extern "C" void kernel_launch(void* const* d_in, const int* in_sizes, int n_in,
                              void* d_out, int out_size, void* d_ws, size_t ws_size,
                              hipStream_t stream) {
  const float* x   = (const float*)d_in[0];
  const int*   ei  = (const int*)d_in[1];
  const float* W1  = (const float*)d_in[2];
  const float* as1 = (const float*)d_in[3];
  const float* ad1 = (const float*)d_in[4];
  const float* b1  = (const float*)d_in[5];
  const float* W2  = (const float*)d_in[6];
  const float* as2 = (const float*)d_in[7];
  const float* ad2 = (const float*)d_in[8];
  const float* b2  = (const float*)d_in[9];
  const float* Wc  = (const float*)d_in[10];
  const float* bc  = (const float*)d_in[11];
  float* out = (float*)d_out;

  char* w = (char*)d_ws;
  size_t off = 0;
  unsigned short* H16  = (unsigned short*)(w + off); off = alignup(off + (size_t)NN * HF * 2);
  unsigned short* Xhi  = (unsigned short*)(w + off); off = alignup(off + (size_t)NN * FM * 2);
  unsigned short* Xlo  = (unsigned short*)(w + off); off = alignup(off + (size_t)NN * FM * 2);
  unsigned short* WThi = (unsigned short*)(w + off); off = alignup(off + (size_t)HF * FM * 2);
  unsigned short* WTlo = (unsigned short*)(w + off); off = alignup(off + (size_t)HF * FM * 2);
  float* Sbuf = (float*)(w + off); off = alignup(off + (size_t)NN * NH * 4);
  float* Dbuf = (float*)(w + off); off = alignup(off + (size_t)NN * NH * 4);
  float* X1   = (float*)(w + off); off = alignup(off + (size_t)NN * FM * 4);
  float* X2   = (float*)(w + off); off = alignup(off + (size_t)NN * FM * 4);
  float* WcT  = (float*)(w + off); off = alignup(off + (size_t)OC * 2 * FM * 4);
  int* counts = (int*)(w + off);   off = alignup(off + (size_t)NN * 4);
  int* rowst  = (int*)(w + off);   off = alignup(off + (size_t)(NN + 1) * 4);
  int* cursor = (int*)(w + off);   off = alignup(off + (size_t)NN * 4);
  int* csrsrc = (int*)(w + off);   off = alignup(off + (size_t)ET * 4);

  // CSR by dst (rebuilt every call; ws is re-poisoned)
  k_init_counts<<<(NN + 255) / 256, 256, 0, stream>>>(counts);
  k_count<<<(EE + 255) / 256, 256, 0, stream>>>(ei, counts);
  k_scan<<<1, 1024, 0, stream>>>(counts, rowst, cursor);
  k_fill<<<(ET + 255) / 256, 256, 0, stream>>>(ei, cursor, csrsrc);

  dim3 gGemm((NN + 63) / 64, HF / 256);
  // layer 1
  k_prep_w<<<(FM * HF + 255) / 256, 256, 0, stream>>>(W1, WThi, WTlo);
  k_split_x<<<(NN * FM + 255) / 256, 256, 0, stream>>>(x, Xhi, Xlo);
  k_zero_sd<<<(NN * NH + 255) / 256, 256, 0, stream>>>(Sbuf, Dbuf);
  k_gemm_mfma<<<gGemm, 256, 0, stream>>>(Xhi, Xlo, WThi, WTlo, as1, ad1,
                                         H16, Sbuf, Dbuf);
  k_agg<<<(NN + 3) / 4, 256, 0, stream>>>(H16, Sbuf, Dbuf, rowst, csrsrc, b1,
                                          X1, Xhi, Xlo);
  // layer 2
  k_prep_w<<<(FM * HF + 255) / 256, 256, 0, stream>>>(W2, WThi, WTlo);
  k_zero_sd<<<(NN * NH + 255) / 256, 256, 0, stream>>>(Sbuf, Dbuf);
  k_gemm_mfma<<<gGemm, 256, 0, stream>>>(Xhi, Xlo, WThi, WTlo, as2, ad2,
                                         H16, Sbuf, Dbuf);
  k_agg<<<(NN + 3) / 4, 256, 0, stream>>>(H16, Sbuf, Dbuf, rowst, csrsrc, b2,
                                          X2, Xhi, Xlo);
  // classifier + outputs
  k_transpose_wc<<<(OC * 2 * FM + 255) / 256, 256, 0, stream>>>(Wc, WcT);
  k_emb<<<(NN + 63) / 64, 256, 0, stream>>>(X1, X2, WcT, bc, out);
  k_outer<<<dim3((MIRN + 63) / 64, (CIRC + 63) / 64), 256, 0, stream>>>(
      out + OFF_CIRC, out + OFF_MIR, out);
}